// Round 7
// baseline (9298.184 us; speedup 1.0000x reference)
//
#include <hip/hip_runtime.h>
#include <hip/hip_bf16.h>
#include <stdint.h>

#define BB 256
#define TT 128
#define DD 32
#define HH 512
#define NL 6

typedef __attribute__((ext_vector_type(8))) short short8;
typedef __attribute__((ext_vector_type(4))) float f32x4;

__device__ __forceinline__ unsigned short f2bf(float f) {
    union { float f; unsigned u; } v; v.f = f;
    unsigned r = v.u + 0x7fff + ((v.u >> 16) & 1);
    return (unsigned short)(r >> 16);
}
__device__ __forceinline__ float bf2f(unsigned short s) {
    union { unsigned u; float f; } v; v.u = ((unsigned)s) << 16;
    return v.f;
}
__device__ __forceinline__ float fsig(float x) { return 1.0f / (1.0f + __expf(-x)); }
__device__ __forceinline__ float ftanh(float x) {
    float e = __expf(-2.0f * fabsf(x));
    float t = (1.0f - e) / (1.0f + e);
    return x < 0.0f ? -t : t;
}

// L1/L2-bypassing ops (coherent at the die-level Infinity Cache across XCDs)
__device__ __forceinline__ int4 g_load16_cc(const void* p) {
    int4 r;
    asm volatile("global_load_dwordx4 %0, %1, off sc0 sc1" : "=v"(r) : "v"(p) : "memory");
    return r;
}
// NOTE: 128-bit asm input operands unsupported (clang "indirect register inputs");
// and `offset:` must precede sc flags, so use two stores with explicit addresses.
__device__ __forceinline__ void g_store16_cc(void* p, int4 v) {
    union { int4 q; unsigned long long d[2]; } u; u.q = v;
    void* p2 = (void*)((char*)p + 8);
    asm volatile("global_store_dwordx2 %0, %1, off sc0 sc1" :: "v"(p), "v"(u.d[0]) : "memory");
    asm volatile("global_store_dwordx2 %0, %1, off sc0 sc1" :: "v"(p2), "v"(u.d[1]) : "memory");
}

__device__ __forceinline__ void poll_ge(unsigned int* p, unsigned target) {
    int guard = 0;
    while (__hip_atomic_load(p, __ATOMIC_RELAXED, __HIP_MEMORY_SCOPE_AGENT) < target &&
           ++guard < (1 << 17)) {}
}

// ---------------- zero sync counters ----------------
__global__ __launch_bounds__(256) void k_zero(unsigned int* __restrict__ p, int n) {
    int i = blockIdx.x * 256 + threadIdx.x;
    if (i < n) p[i] = 0;
}

// ---------------- weight f32 -> bf16 ----------------
__global__ __launch_bounds__(256) void k_convert(const float* __restrict__ wih, const float* __restrict__ whh,
                                                 unsigned short* __restrict__ wih_bf, unsigned short* __restrict__ whh_bf,
                                                 int n4) {
    int i = blockIdx.x * 256 + threadIdx.x;
    if (i >= n4) return;
    float4 a = ((const float4*)wih)[i];
    float4 b = ((const float4*)whh)[i];
    ushort4 ra; ra.x = f2bf(a.x); ra.y = f2bf(a.y); ra.z = f2bf(a.z); ra.w = f2bf(a.w);
    ushort4 rb; rb.x = f2bf(b.x); rb.y = f2bf(b.y); rb.z = f2bf(b.z); rb.w = f2bf(b.w);
    ((ushort4*)wih_bf)[i] = ra;
    ((ushort4*)whh_bf)[i] = rb;
}

// ---------------- input projection: a_bf = bf16(x @ w_proj.T + b) ----------------
__global__ __launch_bounds__(512) void k_proj(const float* __restrict__ x, const float* __restrict__ wp,
                                              const float* __restrict__ bp,
                                              unsigned short* __restrict__ abf) {
    __shared__ float xs[64][DD];
    int m0 = blockIdx.x * 64;
    for (int i = threadIdx.x; i < 64 * DD; i += 512)
        xs[i >> 5][i & 31] = x[(size_t)(m0 + (i >> 5)) * DD + (i & 31)];
    __syncthreads();
    int n = threadIdx.x;
    float w[DD];
#pragma unroll
    for (int k = 0; k < DD; k++) w[k] = wp[n * DD + k];
    float bias = bp[n];
    for (int r = 0; r < 64; r++) {
        float acc = bias;
#pragma unroll
        for (int k = 0; k < DD; k++) acc += xs[r][k] * w[k];
        abf[(size_t)(m0 + r) * HH + n] = f2bf(acc);
    }
}

// ---------------- LN helper: one row-slice, 16 elems per lane ----------------
__device__ __forceinline__ void do_ln(int l, int tln, int row, int li, bool final_out,
                                      const unsigned short* __restrict__ hbuf,
                                      unsigned short* __restrict__ xring,
                                      const float* __restrict__ ln_g, const float* __restrict__ ln_b,
                                      float* __restrict__ xfinal) {
    const unsigned short* hrow = hbuf + ((size_t)(l * 2 + (tln & 1))) * 131072 + (size_t)row * 512 + li * 16;
    int4 h0 = g_load16_cc(hrow);
    int4 h1 = g_load16_cc(hrow + 8);
    int4 r0, r1;
    const bool res = (l > 0);
    if (res) {
        const unsigned short* xrow = xring + ((size_t)((l - 1) * 16 + (tln & 15))) * 131072 + (size_t)row * 512 + li * 16;
        r0 = g_load16_cc(xrow);
        r1 = g_load16_cc(xrow + 8);
    }
    asm volatile("s_waitcnt vmcnt(0)" ::: "memory");
    __builtin_amdgcn_sched_barrier(0);
    const unsigned short* hu0 = (const unsigned short*)&h0;
    const unsigned short* hu1 = (const unsigned short*)&h1;
    float v[16];
    float s = 0.f, ss = 0.f;
#pragma unroll
    for (int e = 0; e < 8; e++) { v[e] = bf2f(hu0[e]); v[e + 8] = bf2f(hu1[e]); }
#pragma unroll
    for (int e = 0; e < 16; e++) { s += v[e]; ss += v[e] * v[e]; }
#pragma unroll
    for (int off = 1; off < 32; off <<= 1) {
        s += __shfl_xor(s, off);
        ss += __shfl_xor(ss, off);
    }
    float mu = s * (1.f / 512.f);
    float var = ss * (1.f / 512.f) - mu * mu;
    float rs = rsqrtf(var + 1e-5f);
    const unsigned short* ru0 = (const unsigned short*)&r0;
    const unsigned short* ru1 = (const unsigned short*)&r1;
    float y[16];
#pragma unroll
    for (int e = 0; e < 16; e++) {
        float yy = (v[e] - mu) * rs * ln_g[l * 512 + li * 16 + e] + ln_b[l * 512 + li * 16 + e];
        if (res) yy += bf2f(e < 8 ? ru0[e] : ru1[e - 8]);
        y[e] = yy;
    }
    if (final_out) {
        float* dst = xfinal + (size_t)row * 512 + li * 16;
#pragma unroll
        for (int q = 0; q < 4; q++)
            *(float4*)(dst + q * 4) = (float4){y[q * 4], y[q * 4 + 1], y[q * 4 + 2], y[q * 4 + 3]};
    } else {
        unsigned short ys[16];
#pragma unroll
        for (int e = 0; e < 16; e++) ys[e] = f2bf(y[e]);
        unsigned short* dst = xring + ((size_t)(l * 16 + (tln & 15))) * 131072 + (size_t)row * 512 + li * 16;
        g_store16_cc(dst, *(int4*)&ys[0]);
        g_store16_cc(dst + 8, *(int4*)&ys[8]);
    }
}

// ---------------- mega kernel: all 6 layers pipelined ----------------
// 192 blocks: blk -> l(6) x g(2 batch groups of 128) x ui(16 unit tiles of 32)
// per block: 128 batches x 32 units; whh slice (128 rows x 512) in LDS.
__global__ __launch_bounds__(256, 1) void k_mega(
    const unsigned short* __restrict__ wih_bf,
    const unsigned short* __restrict__ whh_bf,
    const unsigned short* __restrict__ a_bf,
    const float* __restrict__ bih_all, const float* __restrict__ bhh_all,
    const float* __restrict__ ln_g, const float* __restrict__ ln_b,
    unsigned short* __restrict__ xring,   // [5][16][256][512] bf16
    unsigned short* __restrict__ hbuf,    // [6][2][256][512] bf16
    float* __restrict__ xfinal,           // [256][512] f32
    unsigned int* __restrict__ cnt)       // 24 counters, 64 u32 apart
{
    __shared__ unsigned short smem[128 * 512];   // 128KB whh slice (swizzled)
    __shared__ unsigned short hstage[128 * 40];  // 10KB h transpose staging

    const int blk = blockIdx.x;
    const int l = blk >> 5;
    const int rr_ = blk & 31;
    const int g = rr_ >> 4;
    const int ui = rr_ & 15;
    const int tid = threadIdx.x, lane = tid & 63, w = tid >> 6;
    const int u0 = ui * 32;
    const int gb0 = g * 128;
    const int wb0 = gb0 + w * 32;
    const int uu = lane & 15;
    const int kg = lane >> 4;

    const unsigned short* wih = wih_bf + (size_t)l * 2048 * 512;
    const unsigned short* whh = whh_bf + (size_t)l * 2048 * 512;
    unsigned int* c1  = cnt + (l * 2 + g) * 64;
    unsigned int* c1n = cnt + ((l + 1) * 2 + g) * 64;        // valid only l<5
    unsigned int* c2  = cnt + (12 + l * 2 + g) * 64;
    unsigned int* c2u = cnt + (12 + (l - 1) * 2 + g) * 64;   // valid only l>0

    // stage whh slice: LDS row rr = (gate*2+usub)*16 + i -> global row gate*512 + u0 + usub*16 + i
    for (int c = tid; c < 128 * 64; c += 256) {
        int rr = c >> 6, k16 = c & 63;
        int grow = (rr >> 5) * 512 + u0 + ((rr >> 4) & 1) * 16 + (rr & 15);
        int4 v = *(const int4*)(whh + (size_t)grow * 512 + k16 * 8);
        int baddr = (rr * 1024 + k16 * 16) ^ ((rr & 7) << 4);
        *(int4*)((char*)smem + baddr) = v;
    }
    __syncthreads();

    float biasg[8];
#pragma unroll
    for (int rt = 0; rt < 8; rt++) {
        int grow = (rt >> 1) * 512 + u0 + ((rt & 1) << 4) + uu;
        biasg[rt] = bih_all[l * 2048 + grow] + bhh_all[l * 2048 + grow];
    }

    const int ln_row = gb0 + ui * 8 + w * 2 + (lane >> 5);   // LN row for this lane
    const int li = lane & 31;
    f32x4 cst[4];
#pragma unroll
    for (int q = 0; q < 4; q++) cst[q] = (f32x4){0.f, 0.f, 0.f, 0.f};

#pragma unroll 1
    for (int t = 0; t < TT; ++t) {
        // ---- top polls: own h(t-1) ready; downstream far enough for ring reuse ----
        if (tid == 0) {
            if (t > 0) poll_ge(c1, 16u * (unsigned)t);
            if (l < 5 && t >= 17) poll_ge(c1n, 16u * (unsigned)(t - 15));
        }
        __syncthreads();

        // ---- LN(t-1) -> x_{l+1} ring (producer-side) ----
        if (t > 0 && l < 5) {
            do_ln(l, t - 1, ln_row, li, false, hbuf, xring, ln_g, ln_b, xfinal);
            asm volatile("s_waitcnt vmcnt(0)" ::: "memory");
            __syncthreads();
            if (tid == 0)
                __hip_atomic_fetch_add(c2, 1u, __ATOMIC_RELAXED, __HIP_MEMORY_SCOPE_AGENT);
        }

        // ---- wait for own input x(t) ----
        if (l > 0) {
            if (tid == 0) poll_ge(c2u, 16u * (unsigned)(t + 1));
            __syncthreads();
        }

        // ---- x-pass: acc = bias + x(t) @ wih.T ----
        f32x4 acc[2][8];
#pragma unroll
        for (int bt = 0; bt < 2; bt++)
#pragma unroll
            for (int rt = 0; rt < 8; rt++)
                acc[bt][rt] = (f32x4){biasg[rt], biasg[rt], biasg[rt], biasg[rt]};

#pragma unroll
        for (int half = 0; half < 2; half++) {
            short8 ax[2][8];
            if (l == 0) {
#pragma unroll
                for (int bt = 0; bt < 2; bt++)
#pragma unroll
                    for (int k8 = 0; k8 < 8; k8++)
                        ax[bt][k8] = *(const short8*)(a_bf + ((size_t)(wb0 + bt * 16 + uu) * TT + t) * 512 +
                                                      (half * 8 + k8) * 32 + kg * 8);
            } else {
                const unsigned short* xs = xring + ((size_t)((l - 1) * 16 + (t & 15))) * 131072;
                int4 ai[2][8];
#pragma unroll
                for (int bt = 0; bt < 2; bt++)
#pragma unroll
                    for (int k8 = 0; k8 < 8; k8++)
                        ai[bt][k8] = g_load16_cc(xs + (size_t)(wb0 + bt * 16 + uu) * 512 +
                                                 (half * 8 + k8) * 32 + kg * 8);
                asm volatile("s_waitcnt vmcnt(0)" ::: "memory");
                __builtin_amdgcn_sched_barrier(0);
#pragma unroll
                for (int bt = 0; bt < 2; bt++)
#pragma unroll
                    for (int k8 = 0; k8 < 8; k8++)
                        ax[bt][k8] = *(short8*)&ai[bt][k8];
            }
#pragma unroll
            for (int k8 = 0; k8 < 8; k8++) {
                int ks = half * 8 + k8;
#pragma unroll
                for (int rt = 0; rt < 8; rt++) {
                    short8 bfr = *(const short8*)(wih + (size_t)((rt >> 1) * 512 + u0 + ((rt & 1) << 4) + uu) * 512 +
                                                  ks * 32 + kg * 8);
                    acc[0][rt] = __builtin_amdgcn_mfma_f32_16x16x32_bf16(ax[0][k8], bfr, acc[0][rt], 0, 0, 0);
                    acc[1][rt] = __builtin_amdgcn_mfma_f32_16x16x32_bf16(ax[1][k8], bfr, acc[1][rt], 0, 0, 0);
                }
            }
        }

        // ---- h-pass: acc += h(t-1) @ whh.T ----
        if (t > 0) {
            const unsigned short* hp = hbuf + ((size_t)(l * 2 + ((t - 1) & 1))) * 131072;
#pragma unroll
            for (int half = 0; half < 2; half++) {
                int4 ai[2][8];
#pragma unroll
                for (int bt = 0; bt < 2; bt++)
#pragma unroll
                    for (int k8 = 0; k8 < 8; k8++)
                        ai[bt][k8] = g_load16_cc(hp + (size_t)(wb0 + bt * 16 + uu) * 512 +
                                                 (half * 8 + k8) * 32 + kg * 8);
                asm volatile("s_waitcnt vmcnt(0)" ::: "memory");
                __builtin_amdgcn_sched_barrier(0);
#pragma unroll
                for (int k8 = 0; k8 < 8; k8++) {
                    int k2 = ((half * 8 + k8) * 32 + kg * 8) * 2;
                    short8 ah0 = *(short8*)&ai[0][k8];
                    short8 ah1 = *(short8*)&ai[1][k8];
#pragma unroll
                    for (int rt = 0; rt < 8; rt++) {
                        int rr = rt * 16 + uu;
                        int baddr = (rr * 1024 + k2) ^ ((rr & 7) << 4);
                        short8 bh = *(const short8*)((const char*)smem + baddr);
                        acc[0][rt] = __builtin_amdgcn_mfma_f32_16x16x32_bf16(ah0, bh, acc[0][rt], 0, 0, 0);
                        acc[1][rt] = __builtin_amdgcn_mfma_f32_16x16x32_bf16(ah1, bh, acc[1][rt], 0, 0, 0);
                    }
                }
            }
        }

        // ---- activations + c update; stage h into LDS ----
#pragma unroll
        for (int bt = 0; bt < 2; bt++)
#pragma unroll
            for (int usub = 0; usub < 2; usub++) {
                f32x4 iq = acc[bt][0 + usub], fq = acc[bt][2 + usub];
                f32x4 gq = acc[bt][4 + usub], oq = acc[bt][6 + usub];
#pragma unroll
                for (int j = 0; j < 4; j++) {
                    float i_ = fsig(iq[j]);
                    float f_ = fsig(fq[j]);
                    float g_ = ftanh(gq[j]);
                    float o_ = fsig(oq[j]);
                    float c = f_ * cst[bt * 2 + usub][j] + i_ * g_;
                    cst[bt * 2 + usub][j] = c;
                    float h = o_ * ftanh(c);
                    hstage[(w * 32 + bt * 16 + kg * 4 + j) * 40 + usub * 16 + uu] = f2bf(h);
                }
            }
        __syncthreads();
        // coalesced sc1 store of h(t) tile (128 batches x 32 units)
        {
            int lb = tid >> 1, hf = tid & 1;
            int4 v0 = *(const int4*)(hstage + lb * 40 + hf * 16);
            int4 v1 = *(const int4*)(hstage + lb * 40 + hf * 16 + 8);
            unsigned short* hd = hbuf + ((size_t)(l * 2 + (t & 1))) * 131072 + (size_t)(gb0 + lb) * 512 + u0 + hf * 16;
            g_store16_cc(hd, v0);
            g_store16_cc(hd + 8, v1);
        }
        asm volatile("s_waitcnt vmcnt(0)" ::: "memory");
        __syncthreads();
        if (tid == 0)
            __hip_atomic_fetch_add(c1, 1u, __ATOMIC_RELAXED, __HIP_MEMORY_SCOPE_AGENT);
    }

    // ---- post-loop: LN(127) ----
    if (tid == 0) poll_ge(c1, 16u * 128u);
    __syncthreads();
    if (l < 5) {
        do_ln(l, TT - 1, ln_row, li, false, hbuf, xring, ln_g, ln_b, xfinal);
        asm volatile("s_waitcnt vmcnt(0)" ::: "memory");
        __syncthreads();
        if (tid == 0)
            __hip_atomic_fetch_add(c2, 1u, __ATOMIC_RELAXED, __HIP_MEMORY_SCOPE_AGENT);
    } else {
        do_ln(l, TT - 1, ln_row, li, true, hbuf, xring, ln_g, ln_b, xfinal);
    }
}

// ---------------- MLP head ----------------
__global__ __launch_bounds__(512) void k_mlp1(const float* __restrict__ xfinal, const float* __restrict__ w1,
                                              const float* __restrict__ b1, float* __restrict__ z1) {
    __shared__ float xs[512];
    int b = blockIdx.x;
    xs[threadIdx.x] = xfinal[(size_t)b * 512 + threadIdx.x];
    __syncthreads();
    int n = threadIdx.x;
    const float4* wr = (const float4*)(w1 + (size_t)n * 512);
    float acc = b1[n];
#pragma unroll 4
    for (int k4 = 0; k4 < 128; k4++) {
        float4 wv = wr[k4];
        acc += xs[k4 * 4 + 0] * wv.x + xs[k4 * 4 + 1] * wv.y + xs[k4 * 4 + 2] * wv.z + xs[k4 * 4 + 3] * wv.w;
    }
    z1[(size_t)b * 512 + n] = fmaxf(acc, 0.f);
}

__global__ __launch_bounds__(256) void k_mlp2(const float* __restrict__ z1, const float* __restrict__ w2,
                                              const float* __restrict__ b2, float* __restrict__ z2) {
    __shared__ float xs[512];
    int b = blockIdx.x;
    xs[threadIdx.x] = z1[(size_t)b * 512 + threadIdx.x];
    xs[threadIdx.x + 256] = z1[(size_t)b * 512 + threadIdx.x + 256];
    __syncthreads();
    int n = threadIdx.x;
    const float4* wr = (const float4*)(w2 + (size_t)n * 512);
    float acc = b2[n];
#pragma unroll 4
    for (int k4 = 0; k4 < 128; k4++) {
        float4 wv = wr[k4];
        acc += xs[k4 * 4 + 0] * wv.x + xs[k4 * 4 + 1] * wv.y + xs[k4 * 4 + 2] * wv.z + xs[k4 * 4 + 3] * wv.w;
    }
    z2[(size_t)b * 256 + n] = fmaxf(acc, 0.f);
}

__global__ __launch_bounds__(256) void k_mlp3(const float* __restrict__ z2, const float* __restrict__ w3,
                                              const float* __restrict__ b3, float* __restrict__ outp) {
    __shared__ float red[4];
    int b = blockIdx.x;
    int tid = threadIdx.x;
    float p = z2[(size_t)b * 256 + tid] * w3[tid];
#pragma unroll
    for (int off = 32; off > 0; off >>= 1) p += __shfl_down(p, off);
    if ((tid & 63) == 0) red[tid >> 6] = p;
    __syncthreads();
    if (tid == 0) outp[b] = red[0] + red[1] + red[2] + red[3] + b3[0];
}

extern "C" void kernel_launch(void* const* d_in, const int* in_sizes, int n_in,
                              void* d_out, int out_size, void* d_ws, size_t ws_size,
                              hipStream_t stream) {
    const float* x      = (const float*)d_in[0];
    const float* w_proj = (const float*)d_in[1];
    const float* b_proj = (const float*)d_in[2];
    const float* w_ih   = (const float*)d_in[3];
    const float* w_hh   = (const float*)d_in[4];
    const float* b_ih   = (const float*)d_in[5];
    const float* b_hh   = (const float*)d_in[6];
    const float* ln_g   = (const float*)d_in[7];
    const float* ln_b   = (const float*)d_in[8];
    const float* w1 = (const float*)d_in[9];  const float* b1 = (const float*)d_in[10];
    const float* w2 = (const float*)d_in[11]; const float* b2 = (const float*)d_in[12];
    const float* w3 = (const float*)d_in[13]; const float* b3 = (const float*)d_in[14];
    float* outp = (float*)d_out;

    char* ws = (char*)d_ws;
    size_t off = 0;
    auto alloc = [&](size_t sz) { char* p = ws + off; off += (sz + 255) & ~(size_t)255; return p; };
    unsigned short* a_bf   = (unsigned short*)alloc((size_t)32768 * 512 * 2);      // 33.5 MB
    unsigned short* wih_bf = (unsigned short*)alloc((size_t)NL * 2048 * 512 * 2);  // 12.6 MB
    unsigned short* whh_bf = (unsigned short*)alloc((size_t)NL * 2048 * 512 * 2);  // 12.6 MB
    unsigned short* xring  = (unsigned short*)alloc((size_t)5 * 16 * 256 * 512 * 2); // 21 MB
    unsigned short* hbuf   = (unsigned short*)alloc((size_t)6 * 2 * 256 * 512 * 2);  // 3.1 MB
    float*          xfinal = (float*)alloc((size_t)256 * 512 * 4);                  // 0.5 MB
    float*          z1     = (float*)alloc((size_t)256 * 512 * 4);
    float*          z2     = (float*)alloc((size_t)256 * 256 * 4);
    unsigned int*   cnt    = (unsigned int*)alloc(2048 * 4);

    k_zero<<<8, 256, 0, stream>>>(cnt, 2048);
    k_convert<<<6144, 256, 0, stream>>>(w_ih, w_hh, wih_bf, whh_bf, (NL * 2048 * 512) / 4);
    k_proj<<<512, 512, 0, stream>>>(x, w_proj, b_proj, a_bf);

    k_mega<<<192, 256, 0, stream>>>(wih_bf, whh_bf, a_bf, b_ih, b_hh, ln_g, ln_b,
                                    xring, hbuf, xfinal, cnt);

    k_mlp1<<<256, 512, 0, stream>>>(xfinal, w1, b1, z1);
    k_mlp2<<<256, 256, 0, stream>>>(z1, w2, b2, z2);
    k_mlp3<<<256, 256, 0, stream>>>(z2, w3, b3, outp);
}

// Round 8
// 9013.554 us; speedup vs baseline: 1.0316x; 1.0316x over previous
//
#include <hip/hip_runtime.h>
#include <hip/hip_bf16.h>
#include <stdint.h>

#define BB 256
#define TT 128
#define DD 32
#define HH 512
#define NL 6

typedef __attribute__((ext_vector_type(8))) short short8;
typedef __attribute__((ext_vector_type(4))) float f32x4;

__device__ __forceinline__ unsigned short f2bf(float f) {
    union { float f; unsigned u; } v; v.f = f;
    unsigned r = v.u + 0x7fff + ((v.u >> 16) & 1);
    return (unsigned short)(r >> 16);
}
__device__ __forceinline__ float bf2f(unsigned short s) {
    union { unsigned u; float f; } v; v.u = ((unsigned)s) << 16;
    return v.f;
}
__device__ __forceinline__ float fsig(float x) { return 1.0f / (1.0f + __expf(-x)); }
__device__ __forceinline__ float ftanh(float x) {
    float e = __expf(-2.0f * fabsf(x));
    float t = (1.0f - e) / (1.0f + e);
    return x < 0.0f ? -t : t;
}

// Transposed exchange-tile addressing: [slot][ks 0..15][kg 0..3][row 0..255][8 elems]
// chunk of 8 bf16 = 16B; slot size = 16*4*256*8 = 131072 shorts (256 KB)
__device__ __forceinline__ size_t xt_off(int slot, int ks, int kg, int row) {
    return ((((size_t)slot * 16 + ks) * 4 + kg) * 256 + row) * 8;
}

// L1/L2-bypassing ops (coherent at the die-level Infinity Cache across XCDs)
__device__ __forceinline__ int4 g_load16_cc(const void* p) {
    int4 r;
    asm volatile("global_load_dwordx4 %0, %1, off sc0 sc1" : "=v"(r) : "v"(p) : "memory");
    return r;
}
__device__ __forceinline__ void g_store16_cc(void* p, int4 v) {
    union { int4 q; unsigned long long d[2]; } u; u.q = v;
    void* p2 = (void*)((char*)p + 8);
    asm volatile("global_store_dwordx2 %0, %1, off sc0 sc1" :: "v"(p), "v"(u.d[0]) : "memory");
    asm volatile("global_store_dwordx2 %0, %1, off sc0 sc1" :: "v"(p2), "v"(u.d[1]) : "memory");
}

__device__ __forceinline__ void poll_ge(unsigned int* p, unsigned target) {
    int guard = 0;
    while (__hip_atomic_load(p, __ATOMIC_RELAXED, __HIP_MEMORY_SCOPE_AGENT) < target &&
           ++guard < (1 << 17)) {}
}

// ---------------- zero sync counters ----------------
__global__ __launch_bounds__(256) void k_zero(unsigned int* __restrict__ p, int n) {
    int i = blockIdx.x * 256 + threadIdx.x;
    if (i < n) p[i] = 0;
}

// ---------------- weight f32 -> bf16 ----------------
__global__ __launch_bounds__(256) void k_convert(const float* __restrict__ wih, const float* __restrict__ whh,
                                                 unsigned short* __restrict__ wih_bf, unsigned short* __restrict__ whh_bf,
                                                 int n4) {
    int i = blockIdx.x * 256 + threadIdx.x;
    if (i >= n4) return;
    float4 a = ((const float4*)wih)[i];
    float4 b = ((const float4*)whh)[i];
    ushort4 ra; ra.x = f2bf(a.x); ra.y = f2bf(a.y); ra.z = f2bf(a.z); ra.w = f2bf(a.w);
    ushort4 rb; rb.x = f2bf(b.x); rb.y = f2bf(b.y); rb.z = f2bf(b.z); rb.w = f2bf(b.w);
    ((ushort4*)wih_bf)[i] = ra;
    ((ushort4*)whh_bf)[i] = rb;
}

// ---------------- input projection -> transposed a_bfT[t][ks][kg][b][8] ----------------
__global__ __launch_bounds__(512) void k_proj(const float* __restrict__ x, const float* __restrict__ wp,
                                              const float* __restrict__ bp,
                                              unsigned short* __restrict__ abfT) {
    __shared__ float xs[64][DD];
    int m0 = blockIdx.x * 64;
    for (int i = threadIdx.x; i < 64 * DD; i += 512)
        xs[i >> 5][i & 31] = x[(size_t)(m0 + (i >> 5)) * DD + (i & 31)];
    __syncthreads();
    int n = threadIdx.x;
    float w[DD];
#pragma unroll
    for (int k = 0; k < DD; k++) w[k] = wp[n * DD + k];
    float bias = bp[n];
    const int ks = n >> 5, kg = (n >> 3) & 3, e = n & 7;
    for (int r = 0; r < 64; r++) {
        float acc = bias;
#pragma unroll
        for (int k = 0; k < DD; k++) acc += xs[r][k] * w[k];
        int flat = m0 + r;
        int b = flat >> 7, t = flat & 127;
        abfT[xt_off(t, ks, kg, b) + e] = f2bf(acc);
    }
}

// ---------------- LN helper: one row, 16 elems per lane (transposed chunks) ----------------
__device__ __forceinline__ void do_ln(int l, int tln, int row, int li, bool final_out,
                                      const unsigned short* __restrict__ hbuf,
                                      unsigned short* __restrict__ xring,
                                      const float* __restrict__ ln_g, const float* __restrict__ ln_b,
                                      float* __restrict__ xfinal) {
    const int ks = li >> 1, kgb = (li & 1) * 2;
    int4 h0 = g_load16_cc(hbuf + xt_off(l * 2 + (tln & 1), ks, kgb, row));
    int4 h1 = g_load16_cc(hbuf + xt_off(l * 2 + (tln & 1), ks, kgb + 1, row));
    int4 r0, r1;
    const bool res = (l > 0);
    if (res) {
        int slot = (l - 1) * 16 + (tln & 15);
        r0 = g_load16_cc(xring + xt_off(slot, ks, kgb, row));
        r1 = g_load16_cc(xring + xt_off(slot, ks, kgb + 1, row));
    }
    asm volatile("s_waitcnt vmcnt(0)" ::: "memory");
    __builtin_amdgcn_sched_barrier(0);
    const unsigned short* hu0 = (const unsigned short*)&h0;
    const unsigned short* hu1 = (const unsigned short*)&h1;
    float v[16];
    float s = 0.f, ss = 0.f;
#pragma unroll
    for (int e = 0; e < 8; e++) { v[e] = bf2f(hu0[e]); v[e + 8] = bf2f(hu1[e]); }
#pragma unroll
    for (int e = 0; e < 16; e++) { s += v[e]; ss += v[e] * v[e]; }
#pragma unroll
    for (int off = 1; off < 32; off <<= 1) {
        s += __shfl_xor(s, off);
        ss += __shfl_xor(ss, off);
    }
    float mu = s * (1.f / 512.f);
    float var = ss * (1.f / 512.f) - mu * mu;
    float rs = rsqrtf(var + 1e-5f);
    const unsigned short* ru0 = (const unsigned short*)&r0;
    const unsigned short* ru1 = (const unsigned short*)&r1;
    float y[16];
#pragma unroll
    for (int e = 0; e < 16; e++) {
        float yy = (v[e] - mu) * rs * ln_g[l * 512 + li * 16 + e] + ln_b[l * 512 + li * 16 + e];
        if (res) yy += bf2f(e < 8 ? ru0[e] : ru1[e - 8]);
        y[e] = yy;
    }
    if (final_out) {
        float* dst = xfinal + (size_t)row * 512 + li * 16;
#pragma unroll
        for (int q = 0; q < 4; q++)
            *(float4*)(dst + q * 4) = (float4){y[q * 4], y[q * 4 + 1], y[q * 4 + 2], y[q * 4 + 3]};
    } else {
        unsigned short ys[16];
#pragma unroll
        for (int e = 0; e < 16; e++) ys[e] = f2bf(y[e]);
        int slot = l * 16 + (tln & 15);
        g_store16_cc(xring + xt_off(slot, ks, kgb, row), *(int4*)&ys[0]);
        g_store16_cc(xring + xt_off(slot, ks, kgb + 1, row), *(int4*)&ys[8]);
    }
}

// ---------------- mega kernel: all 6 layers pipelined ----------------
// 192 blocks: blk -> l(6) x g(2 batch groups of 128) x ui(16 unit tiles of 32)
__global__ __launch_bounds__(256, 1) void k_mega(
    const unsigned short* __restrict__ wih_bf,
    const unsigned short* __restrict__ whh_bf,
    const unsigned short* __restrict__ a_bfT,   // [128 slots] transposed
    const float* __restrict__ bih_all, const float* __restrict__ bhh_all,
    const float* __restrict__ ln_g, const float* __restrict__ ln_b,
    unsigned short* __restrict__ xring,   // [80 slots] transposed
    unsigned short* __restrict__ hbuf,    // [12 slots] transposed
    float* __restrict__ xfinal,           // [256][512] f32
    unsigned int* __restrict__ cnt)
{
    __shared__ unsigned short smem[128 * 512];   // 128KB whh slice (swizzled)
    __shared__ unsigned short hstage[128 * 34];  // h staging, stride 34 (conflict-free readout)

    const int blk = blockIdx.x;
    const int l = blk >> 5;
    const int rr_ = blk & 31;
    const int g = rr_ >> 4;
    const int ui = rr_ & 15;
    const int tid = threadIdx.x, lane = tid & 63, w = tid >> 6;
    const int u0 = ui * 32;
    const int gb0 = g * 128;
    const int wb0 = gb0 + w * 32;
    const int uu = lane & 15;
    const int kg = lane >> 4;

    const unsigned short* wih = wih_bf + (size_t)l * 2048 * 512;
    const unsigned short* whh = whh_bf + (size_t)l * 2048 * 512;
    unsigned int* c1  = cnt + (l * 2 + g) * 64;
    unsigned int* c1n = cnt + ((l + 1) * 2 + g) * 64;        // valid only l<5
    unsigned int* c2  = cnt + (12 + l * 2 + g) * 64;
    unsigned int* c2u = cnt + (12 + (l - 1) * 2 + g) * 64;   // valid only l>0

    // stage whh slice: LDS row rr = (gate*2+usub)*16 + i -> global row gate*512 + u0 + usub*16 + i
    for (int c = tid; c < 128 * 64; c += 256) {
        int rr = c >> 6, k16 = c & 63;
        int grow = (rr >> 5) * 512 + u0 + ((rr >> 4) & 1) * 16 + (rr & 15);
        int4 v = *(const int4*)(whh + (size_t)grow * 512 + k16 * 8);
        int baddr = (rr * 1024 + k16 * 16) ^ ((rr & 7) << 4);
        *(int4*)((char*)smem + baddr) = v;
    }
    __syncthreads();

    float biasg[8];
#pragma unroll
    for (int rt = 0; rt < 8; rt++) {
        int grow = (rt >> 1) * 512 + u0 + ((rt & 1) << 4) + uu;
        biasg[rt] = bih_all[l * 2048 + grow] + bhh_all[l * 2048 + grow];
    }

    const int ln_row = gb0 + ui * 8 + w * 2 + (lane >> 5);
    const int li = lane & 31;
    f32x4 cst[4];
#pragma unroll
    for (int q = 0; q < 4; q++) cst[q] = (f32x4){0.f, 0.f, 0.f, 0.f};

#pragma unroll 1
    for (int t = 0; t < TT; ++t) {
        // ---- top polls ----
        if (tid == 0) {
            if (t > 0) poll_ge(c1, 16u * (unsigned)t);
            if (l < 5 && t >= 17) poll_ge(c1n, 16u * (unsigned)(t - 15));
        }
        __syncthreads();

        // ---- LN(t-1) -> x_{l+1} ring ----
        if (t > 0 && l < 5) {
            do_ln(l, t - 1, ln_row, li, false, hbuf, xring, ln_g, ln_b, xfinal);
            asm volatile("s_waitcnt vmcnt(0)" ::: "memory");
            __syncthreads();
            if (tid == 0)
                __hip_atomic_fetch_add(c2, 1u, __ATOMIC_RELAXED, __HIP_MEMORY_SCOPE_AGENT);
        }

        // ---- wait for own input x(t) ----
        if (l > 0) {
            if (tid == 0) poll_ge(c2u, 16u * (unsigned)(t + 1));
            __syncthreads();
        }

        // ---- x-pass: acc = bias + x(t) @ wih.T ----
        f32x4 acc[2][8];
#pragma unroll
        for (int bt = 0; bt < 2; bt++)
#pragma unroll
            for (int rt = 0; rt < 8; rt++)
                acc[bt][rt] = (f32x4){biasg[rt], biasg[rt], biasg[rt], biasg[rt]};

#pragma unroll
        for (int half = 0; half < 2; half++) {
            short8 ax[2][8];
            if (l == 0) {
#pragma unroll
                for (int bt = 0; bt < 2; bt++)
#pragma unroll
                    for (int k8 = 0; k8 < 8; k8++)
                        ax[bt][k8] = *(const short8*)(a_bfT + xt_off(t, half * 8 + k8, kg, wb0 + bt * 16 + uu));
            } else {
                int slot = (l - 1) * 16 + (t & 15);
                int4 ai[2][8];
#pragma unroll
                for (int bt = 0; bt < 2; bt++)
#pragma unroll
                    for (int k8 = 0; k8 < 8; k8++)
                        ai[bt][k8] = g_load16_cc(xring + xt_off(slot, half * 8 + k8, kg, wb0 + bt * 16 + uu));
                asm volatile("s_waitcnt vmcnt(0)" ::: "memory");
                __builtin_amdgcn_sched_barrier(0);
#pragma unroll
                for (int bt = 0; bt < 2; bt++)
#pragma unroll
                    for (int k8 = 0; k8 < 8; k8++)
                        ax[bt][k8] = *(short8*)&ai[bt][k8];
            }
#pragma unroll
            for (int k8 = 0; k8 < 8; k8++) {
                int ks = half * 8 + k8;
#pragma unroll
                for (int rt = 0; rt < 8; rt++) {
                    short8 bfr = *(const short8*)(wih + (size_t)((rt >> 1) * 512 + u0 + ((rt & 1) << 4) + uu) * 512 +
                                                  ks * 32 + kg * 8);
                    acc[0][rt] = __builtin_amdgcn_mfma_f32_16x16x32_bf16(ax[0][k8], bfr, acc[0][rt], 0, 0, 0);
                    acc[1][rt] = __builtin_amdgcn_mfma_f32_16x16x32_bf16(ax[1][k8], bfr, acc[1][rt], 0, 0, 0);
                }
            }
        }

        // ---- h-pass: acc += h(t-1) @ whh.T ----
        if (t > 0) {
            const int hslot = l * 2 + ((t - 1) & 1);
#pragma unroll
            for (int half = 0; half < 2; half++) {
                int4 ai[2][8];
#pragma unroll
                for (int bt = 0; bt < 2; bt++)
#pragma unroll
                    for (int k8 = 0; k8 < 8; k8++)
                        ai[bt][k8] = g_load16_cc(hbuf + xt_off(hslot, half * 8 + k8, kg, wb0 + bt * 16 + uu));
                asm volatile("s_waitcnt vmcnt(0)" ::: "memory");
                __builtin_amdgcn_sched_barrier(0);
#pragma unroll
                for (int k8 = 0; k8 < 8; k8++) {
                    int k2 = ((half * 8 + k8) * 32 + kg * 8) * 2;
                    short8 ah0 = *(short8*)&ai[0][k8];
                    short8 ah1 = *(short8*)&ai[1][k8];
#pragma unroll
                    for (int rt = 0; rt < 8; rt++) {
                        int rr = rt * 16 + uu;
                        int baddr = (rr * 1024 + k2) ^ ((rr & 7) << 4);
                        short8 bh = *(const short8*)((const char*)smem + baddr);
                        acc[0][rt] = __builtin_amdgcn_mfma_f32_16x16x32_bf16(ah0, bh, acc[0][rt], 0, 0, 0);
                        acc[1][rt] = __builtin_amdgcn_mfma_f32_16x16x32_bf16(ah1, bh, acc[1][rt], 0, 0, 0);
                    }
                }
            }
        }

        // ---- activations + c update; stage h into LDS ----
#pragma unroll
        for (int bt = 0; bt < 2; bt++)
#pragma unroll
            for (int usub = 0; usub < 2; usub++) {
                f32x4 iq = acc[bt][0 + usub], fq = acc[bt][2 + usub];
                f32x4 gq = acc[bt][4 + usub], oq = acc[bt][6 + usub];
#pragma unroll
                for (int j = 0; j < 4; j++) {
                    float i_ = fsig(iq[j]);
                    float f_ = fsig(fq[j]);
                    float g_ = ftanh(gq[j]);
                    float o_ = fsig(oq[j]);
                    float c = f_ * cst[bt * 2 + usub][j] + i_ * g_;
                    cst[bt * 2 + usub][j] = c;
                    float h = o_ * ftanh(c);
                    hstage[(w * 32 + bt * 16 + kg * 4 + j) * 34 + usub * 16 + uu] = f2bf(h);
                }
            }
        __syncthreads();
        // transposed, coalesced h(t) store: block owns ks=ui, writes [kg'][row'] chunks
        {
            const int hdst = l * 2 + (t & 1);
#pragma unroll
            for (int c = 0; c < 2; c++) {
                int idx = c * 256 + tid;
                int kgp = idx >> 7, rowp = idx & 127;
                int4 v = *(const int4*)(hstage + rowp * 34 + kgp * 8);
                g_store16_cc(hbuf + xt_off(hdst, ui, kgp, gb0 + rowp), v);
            }
        }
        asm volatile("s_waitcnt vmcnt(0)" ::: "memory");
        __syncthreads();
        if (tid == 0)
            __hip_atomic_fetch_add(c1, 1u, __ATOMIC_RELAXED, __HIP_MEMORY_SCOPE_AGENT);
    }

    // ---- post-loop: LN(127) ----
    if (tid == 0) poll_ge(c1, 16u * 128u);
    __syncthreads();
    if (l < 5) {
        do_ln(l, TT - 1, ln_row, li, false, hbuf, xring, ln_g, ln_b, xfinal);
        asm volatile("s_waitcnt vmcnt(0)" ::: "memory");
        __syncthreads();
        if (tid == 0)
            __hip_atomic_fetch_add(c2, 1u, __ATOMIC_RELAXED, __HIP_MEMORY_SCOPE_AGENT);
    } else {
        do_ln(l, TT - 1, ln_row, li, true, hbuf, xring, ln_g, ln_b, xfinal);
    }
}

// ---------------- MLP head ----------------
__global__ __launch_bounds__(512) void k_mlp1(const float* __restrict__ xfinal, const float* __restrict__ w1,
                                              const float* __restrict__ b1, float* __restrict__ z1) {
    __shared__ float xs[512];
    int b = blockIdx.x;
    xs[threadIdx.x] = xfinal[(size_t)b * 512 + threadIdx.x];
    __syncthreads();
    int n = threadIdx.x;
    const float4* wr = (const float4*)(w1 + (size_t)n * 512);
    float acc = b1[n];
#pragma unroll 4
    for (int k4 = 0; k4 < 128; k4++) {
        float4 wv = wr[k4];
        acc += xs[k4 * 4 + 0] * wv.x + xs[k4 * 4 + 1] * wv.y + xs[k4 * 4 + 2] * wv.z + xs[k4 * 4 + 3] * wv.w;
    }
    z1[(size_t)b * 512 + n] = fmaxf(acc, 0.f);
}

__global__ __launch_bounds__(256) void k_mlp2(const float* __restrict__ z1, const float* __restrict__ w2,
                                              const float* __restrict__ b2, float* __restrict__ z2) {
    __shared__ float xs[512];
    int b = blockIdx.x;
    xs[threadIdx.x] = z1[(size_t)b * 512 + threadIdx.x];
    xs[threadIdx.x + 256] = z1[(size_t)b * 512 + threadIdx.x + 256];
    __syncthreads();
    int n = threadIdx.x;
    const float4* wr = (const float4*)(w2 + (size_t)n * 512);
    float acc = b2[n];
#pragma unroll 4
    for (int k4 = 0; k4 < 128; k4++) {
        float4 wv = wr[k4];
        acc += xs[k4 * 4 + 0] * wv.x + xs[k4 * 4 + 1] * wv.y + xs[k4 * 4 + 2] * wv.z + xs[k4 * 4 + 3] * wv.w;
    }
    z2[(size_t)b * 256 + n] = fmaxf(acc, 0.f);
}

__global__ __launch_bounds__(256) void k_mlp3(const float* __restrict__ z2, const float* __restrict__ w3,
                                              const float* __restrict__ b3, float* __restrict__ outp) {
    __shared__ float red[4];
    int b = blockIdx.x;
    int tid = threadIdx.x;
    float p = z2[(size_t)b * 256 + tid] * w3[tid];
#pragma unroll
    for (int off = 32; off > 0; off >>= 1) p += __shfl_down(p, off);
    if ((tid & 63) == 0) red[tid >> 6] = p;
    __syncthreads();
    if (tid == 0) outp[b] = red[0] + red[1] + red[2] + red[3] + b3[0];
}

extern "C" void kernel_launch(void* const* d_in, const int* in_sizes, int n_in,
                              void* d_out, int out_size, void* d_ws, size_t ws_size,
                              hipStream_t stream) {
    const float* x      = (const float*)d_in[0];
    const float* w_proj = (const float*)d_in[1];
    const float* b_proj = (const float*)d_in[2];
    const float* w_ih   = (const float*)d_in[3];
    const float* w_hh   = (const float*)d_in[4];
    const float* b_ih   = (const float*)d_in[5];
    const float* b_hh   = (const float*)d_in[6];
    const float* ln_g   = (const float*)d_in[7];
    const float* ln_b   = (const float*)d_in[8];
    const float* w1 = (const float*)d_in[9];  const float* b1 = (const float*)d_in[10];
    const float* w2 = (const float*)d_in[11]; const float* b2 = (const float*)d_in[12];
    const float* w3 = (const float*)d_in[13]; const float* b3 = (const float*)d_in[14];
    float* outp = (float*)d_out;

    char* ws = (char*)d_ws;
    size_t off = 0;
    auto alloc = [&](size_t sz) { char* p = ws + off; off += (sz + 255) & ~(size_t)255; return p; };
    unsigned short* a_bfT  = (unsigned short*)alloc((size_t)128 * 131072 * 2);     // 33.5 MB
    unsigned short* wih_bf = (unsigned short*)alloc((size_t)NL * 2048 * 512 * 2);  // 12.6 MB
    unsigned short* whh_bf = (unsigned short*)alloc((size_t)NL * 2048 * 512 * 2);  // 12.6 MB
    unsigned short* xring  = (unsigned short*)alloc((size_t)80 * 131072 * 2);      // 21 MB
    unsigned short* hbuf   = (unsigned short*)alloc((size_t)12 * 131072 * 2);      // 3.1 MB
    float*          xfinal = (float*)alloc((size_t)256 * 512 * 4);                 // 0.5 MB
    float*          z1     = (float*)alloc((size_t)256 * 512 * 4);
    float*          z2     = (float*)alloc((size_t)256 * 256 * 4);
    unsigned int*   cnt    = (unsigned int*)alloc(2048 * 4);

    k_zero<<<8, 256, 0, stream>>>(cnt, 2048);
    k_convert<<<6144, 256, 0, stream>>>(w_ih, w_hh, wih_bf, whh_bf, (NL * 2048 * 512) / 4);
    k_proj<<<512, 512, 0, stream>>>(x, w_proj, b_proj, a_bfT);

    k_mega<<<192, 256, 0, stream>>>(wih_bf, whh_bf, a_bfT, b_ih, b_hh, ln_g, ln_b,
                                    xring, hbuf, xfinal, cnt);

    k_mlp1<<<256, 512, 0, stream>>>(xfinal, w1, b1, z1);
    k_mlp2<<<256, 256, 0, stream>>>(z1, w2, b2, z2);
    k_mlp3<<<256, 256, 0, stream>>>(z2, w3, b3, outp);
}